// Round 13
// baseline (540.687 us; speedup 1.0000x reference)
//
#include <hip/hip_runtime.h>
#include <hip/hip_bf16.h>
#include <hip/hip_cooperative_groups.h>
#include <math.h>

namespace cg = cooperative_groups;

typedef __attribute__((ext_vector_type(8))) short short8;
typedef __attribute__((ext_vector_type(4))) float floatx4;
typedef __attribute__((ext_vector_type(2))) float floatx2;
typedef __attribute__((ext_vector_type(4))) unsigned short ushortx4;

__device__ __forceinline__ float bf2f(unsigned short u) {
    union { unsigned int i; float f; } c; c.i = ((unsigned int)u) << 16; return c.f;
}
__device__ __forceinline__ unsigned short f2bf(float f) {
    union { float f; unsigned int i; } c; c.f = f;
    unsigned int x = c.i;
    return (unsigned short)((x + 0x7FFFu + ((x >> 16) & 1u)) >> 16);
}

// ---------- fp8 e4m3fn (OCP) encode/decode ----------
__device__ __forceinline__ unsigned char f2fp8(float f) {
    unsigned int u = __float_as_uint(f);
    unsigned int sign = (u >> 24) & 0x80u;
    unsigned int a = u & 0x7FFFFFFFu;
    if (a >= 0x43E00000u) return (unsigned char)(sign | 0x7Eu);  // saturate at 448
    if (a < 0x3C800000u) {  // below smallest normal 2^-6: denormal units of 2^-9
        int unit = (int)rintf(__uint_as_float(a) * 512.0f);
        return (unsigned char)(sign | (unsigned int)unit);
    }
    unsigned int r = a + 0x7FFFFu + ((a >> 20) & 1u);  // RNE at bit 20
    unsigned int e = (r >> 23) - 120u;
    unsigned int m = (r >> 20) & 7u;
    return (unsigned char)(sign | (e << 3) | m);
}

__device__ __forceinline__ float fp8dec1(unsigned int b) {
    unsigned int s = (b & 0x80u) << 24;
    unsigned int mag = (b & 0x7Fu) << 20;
    return __uint_as_float(s | mag) * __uint_as_float(0x7B800000u);  // * 2^120
}

template <bool W>
__device__ __forceinline__ floatx2 fp8pk2f(unsigned int v) {
#if defined(__has_builtin) && __has_builtin(__builtin_amdgcn_cvt_pk_f32_fp8)
    return __builtin_amdgcn_cvt_pk_f32_fp8(v, W);
#else
    floatx2 r;
    r[0] = fp8dec1((v >> (W ? 16 : 0)) & 0xFFu);
    r[1] = fp8dec1((v >> (W ? 24 : 8)) & 0xFFu);
    return r;
#endif
}

// decode 8 fp8 (as uint2) -> bf16x8 MFMA A-fragment (exact: e4m3 subset of bf16)
__device__ __forceinline__ short8 fp8x8_to_bf16x8(uint2 q) {
    floatx2 p0 = fp8pk2f<false>(q.x), p1 = fp8pk2f<true>(q.x);
    floatx2 p2 = fp8pk2f<false>(q.y), p3 = fp8pk2f<true>(q.y);
    short8 a;
    a[0] = (short)f2bf(p0[0]); a[1] = (short)f2bf(p0[1]);
    a[2] = (short)f2bf(p1[0]); a[3] = (short)f2bf(p1[1]);
    a[4] = (short)f2bf(p2[0]); a[5] = (short)f2bf(p2[1]);
    a[6] = (short)f2bf(p3[0]); a[7] = (short)f2bf(p3[1]);
    return a;
}

// ---------------- weight prep bodies ----------------
__device__ __forceinline__ void prep_w_body(const float* Wl, const float* Wr,
                                            unsigned short* wf, int NOC, int t) {
    int total = 8 * NOC * 64 * 8;
    if (t >= total) return;
    int j = t & 7;
    int lane = (t >> 3) & 63;
    int rest = t >> 9;
    int oc = rest % NOC;
    int ks = rest / NOC;
    int k = ks * 32 + ((lane >> 4) << 3) + j;
    int o = oc * 16 + (lane & 15);
    float v = (k < 128) ? Wl[o * 128 + k] : Wr[o * 128 + (k - 128)];
    wf[t] = f2bf(v);
}

__device__ __forceinline__ void prep_w2_body(const float* Wl, const float* Wr,
                                             unsigned short* wf, int t) {
    int total = 4 * 8 * 64 * 8;
    if (t >= total) return;
    int j = t & 7;
    int lane = (t >> 3) & 63;
    int rest = t >> 9;
    int oc = rest % 8;
    int ks = rest / 8;
    int k = ks * 32 + ((lane >> 4) << 3) + j;
    int o16 = lane & 15;
    float v = (oc < 4) ? Wl[(oc * 16 + o16) * 128 + k] : Wr[((oc - 4) * 16 + o16) * 128 + k];
    wf[t] = f2bf(v);
}

// ================= cooperative fused CSR build + prep =================
// 512 blocks x 256 threads; buckets = dst>>8 (256 nodes), 512 edge partitions.
constexpr int CB = 512;  // blocks / edge partitions / buckets

__global__ __launch_bounds__(256) void k_csr(
    const int* src, const int* dst, int E,
    int* cnt, int* cntoff, int* bsum, unsigned int* ebuf,
    int* rowptr, int* adj, int N,
    const float* x, unsigned char* xq, int n4,
    const float* Wl0, const float* Wr0, unsigned short* w0,
    const float* Wl1, const float* Wr1, unsigned short* w1,
    const float* Wl2, const float* Wr2, unsigned short* w2) {
    cg::grid_group grid = cg::this_grid();
    __shared__ int shm[1024];
    const int t = threadIdx.x, b = blockIdx.x;
    const int chunk = (E + CB - 1) / CB;
    const int lo = min(b * chunk, E), hi = min(lo + chunk, E);

    // ---- phase A: per-partition histogram into cnt + grid-strided prep ----
    shm[t] = 0; shm[t + 256] = 0;
    __syncthreads();
    for (int e = lo + t; e < hi; e += 256) atomicAdd(&shm[dst[e] >> 8], 1);
    __syncthreads();
    cnt[(size_t)t * CB + b] = shm[t];
    cnt[(size_t)(t + 256) * CB + b] = shm[t + 256];
    {   // prep: x->fp8 + 3x weight prep, grid-strided units of 256 threads
        const int cvtU = (n4 + 255) / 256;
        const int P = cvtU + 128 + 128 + 64;
        for (int u = b; u < P; u += CB) {
            if (u < cvtU) {
                int i = u * 256 + t;
                if (i < n4) {
                    float4 v = *(const float4*)(x + i * 4);
                    unsigned int qw = (unsigned int)f2fp8(v.x) | ((unsigned int)f2fp8(v.y) << 8) |
                                      ((unsigned int)f2fp8(v.z) << 16) | ((unsigned int)f2fp8(v.w) << 24);
                    *(unsigned int*)(xq + i * 4) = qw;
                }
            } else if (u < cvtU + 128) {
                prep_w_body(Wl0, Wr0, w0, 8, (u - cvtU) * 256 + t);
            } else if (u < cvtU + 256) {
                prep_w_body(Wl1, Wr1, w1, 8, (u - cvtU - 128) * 256 + t);
            } else {
                prep_w2_body(Wl2, Wr2, w2, (u - cvtU - 256) * 256 + t);
            }
        }
    }
    grid.sync();

    // ---- phase B: exclusive scan of cnt[CB*CB] -> cntoff ----
    const int l0 = b * CB + 2 * t;
    const int e0 = cnt[l0], e1 = cnt[l0 + 1];
    shm[t] = e0 + e1;
    __syncthreads();
    for (int off = 1; off < 256; off <<= 1) {
        int v = (t >= off) ? shm[t - off] : 0;
        __syncthreads();
        shm[t] += v;
        __syncthreads();
    }
    if (t == 255) bsum[b] = shm[255];
    grid.sync();
    if (b == 0) {  // block 0: exclusive scan of bsum[CB]
        int s0 = bsum[2 * t], s1 = bsum[2 * t + 1];
        shm[t] = s0 + s1;
        __syncthreads();
        for (int off = 1; off < 256; off <<= 1) {
            int v = (t >= off) ? shm[t - off] : 0;
            __syncthreads();
            shm[t] += v;
            __syncthreads();
        }
        int exclPair = shm[t] - (s0 + s1);
        bsum[2 * t] = exclPair;
        bsum[2 * t + 1] = exclPair + s0;
    }
    grid.sync();
    shm[t] = e0 + e1;
    __syncthreads();
    for (int off = 1; off < 256; off <<= 1) {
        int v = (t >= off) ? shm[t - off] : 0;
        __syncthreads();
        shm[t] += v;
        __syncthreads();
    }
    {
        int excl = shm[t] - (e0 + e1) + bsum[b];
        cntoff[l0] = excl;
        cntoff[l0 + 1] = excl + e0;
        if (b == CB - 1 && t == 255) cntoff[CB * CB] = excl + e0 + e1;
    }
    grid.sync();

    // ---- phase C: scatter edges into bucket-partitioned ebuf ----
    shm[t] = cntoff[(size_t)t * CB + b];
    shm[t + 256] = cntoff[(size_t)(t + 256) * CB + b];
    shm[512 + t] = 0; shm[768 + t] = 0;
    __syncthreads();
    for (int e = lo + t; e < hi; e += 256) {
        int d = dst[e];
        int cb = d >> 8;
        int slot = atomicAdd(&shm[512 + cb], 1);
        ebuf[shm[cb] + slot] = (unsigned int)src[e] | ((unsigned int)(d & 255) << 17);
    }
    grid.sync();

    // ---- phase D: per-bucket local CSR (rowptr + adj) ----
    if (b < ((N + 255) >> 8)) {
        int* ldeg = shm;
        int* lptr = shm + 256;
        int* lcur = shm + 512;
        int* tsum = shm + 768;
        int bbase = cntoff[(size_t)b * CB];
        int bend = cntoff[(size_t)(b + 1) * CB];
        ldeg[t] = 0; lcur[t] = 0;
        __syncthreads();
        for (int e = bbase + t; e < bend; e += 256) atomicAdd(&ldeg[ebuf[e] >> 17], 1);
        __syncthreads();
        tsum[t] = ldeg[t];
        __syncthreads();
        for (int off = 1; off < 256; off <<= 1) {
            int v = (t >= off) ? tsum[t - off] : 0;
            __syncthreads();
            tsum[t] += v;
            __syncthreads();
        }
        lptr[t] = tsum[t] - ldeg[t];
        __syncthreads();
        int node = b * 256 + t;
        if (node < N) rowptr[node] = bbase + lptr[t];
        if (b == 0 && t == 0) rowptr[N] = E;
        for (int e = bbase + t; e < bend; e += 256) {
            unsigned int pk = ebuf[e];
            int dl = pk >> 17;
            int ls = atomicAdd(&lcur[dl], 1);
            adj[bbase + lptr[dl] + ls] = (int)(pk & 0x1FFFF);
        }
    }
}

// ---------------- fp8 mean aggregation -> fp8 mean (32-lane group per node) ----------------
__global__ __launch_bounds__(256) void k_aggr8(const unsigned char* feat, const int* rowptr,
                                               const int* adj, unsigned char* aggr, int N) {
    int g = (blockIdx.x * blockDim.x + threadIdx.x) >> 5;
    int lane = threadIdx.x & 31;
    if (g >= N) return;
    int lo = rowptr[g], hi = rowptr[g + 1];
    float a0 = 0.f, a1 = 0.f, a2 = 0.f, a3 = 0.f;
    const unsigned char* fb = feat + lane * 4;
    int j = lo;
    for (; j + 8 <= hi; j += 8) {
        unsigned int v[8];
#pragma unroll
        for (int u = 0; u < 8; u++) {
            int s = adj[j + u];
            v[u] = *(const unsigned int*)(fb + (size_t)s * 128);
        }
#pragma unroll
        for (int u = 0; u < 8; u++) {
            floatx2 l2 = fp8pk2f<false>(v[u]);
            floatx2 h2 = fp8pk2f<true>(v[u]);
            a0 += l2[0]; a1 += l2[1]; a2 += h2[0]; a3 += h2[1];
        }
    }
    if (j < hi) {  // masked tail chunk: loads issued back-to-back
        unsigned int v[8];
        float w[8];
#pragma unroll
        for (int u = 0; u < 8; u++) {
            int jj = j + u;
            int s = adj[jj < hi ? jj : hi - 1];
            v[u] = *(const unsigned int*)(fb + (size_t)s * 128);
            w[u] = (jj < hi) ? 1.0f : 0.0f;
        }
#pragma unroll
        for (int u = 0; u < 8; u++) {
            floatx2 l2 = fp8pk2f<false>(v[u]);
            floatx2 h2 = fp8pk2f<true>(v[u]);
            a0 = fmaf(w[u], l2[0], a0);
            a1 = fmaf(w[u], l2[1], a1);
            a2 = fmaf(w[u], h2[0], a2);
            a3 = fmaf(w[u], h2[1], a3);
        }
    }
    float inv = 1.0f / (float)max(hi - lo, 1);
    unsigned int qw = (unsigned int)f2fp8(a0 * inv) | ((unsigned int)f2fp8(a1 * inv) << 8) |
                      ((unsigned int)f2fp8(a2 * inv) << 16) | ((unsigned int)f2fp8(a3 * inv) << 24);
    *(unsigned int*)(aggr + (size_t)g * 128 + lane * 4) = qw;
}

// ---------------- fused transform (DO=128, relu): outq = fp8(relu([aggr|feat] @ W + b)) ----------------
__global__ __launch_bounds__(256) void k_xform(const unsigned char* aggr,
                                               const unsigned char* featq,
                                               const unsigned short* w2f,
                                               const float* bias, unsigned char* outq, int N) {
    __shared__ unsigned short st[64][132];
    const int wave = threadIdx.x >> 6;
    const int lane = threadIdx.x & 63;
    const int row = blockIdx.x * 64 + wave * 16 + (lane & 15);
    const int kq = lane >> 4;
    floatx4 acc[8];
#pragma unroll
    for (int i = 0; i < 8; i++) acc[i] = (floatx4)0.0f;
    const bool rowOK = row < N;
    const unsigned char* arow = aggr + (size_t)row * 128;
    const unsigned char* frow = featq + (size_t)row * 128;
    const short8* bbase = (const short8*)w2f;
#pragma unroll
    for (int ks = 0; ks < 8; ks++) {
        short8 a;
        if (!rowOK) {
            a = (short8)0;
        } else {
            const unsigned char* p =
                (ks < 4) ? (arow + ks * 32 + kq * 8) : (frow + (ks - 4) * 32 + kq * 8);
            a = fp8x8_to_bf16x8(*(const uint2*)p);
        }
#pragma unroll
        for (int oc = 0; oc < 8; oc++) {
            short8 b = bbase[(ks * 8 + oc) * 64 + lane];
            acc[oc] = __builtin_amdgcn_mfma_f32_16x16x32_bf16(a, b, acc[oc], 0, 0, 0);
        }
    }
    const int rl = wave * 16 + kq * 4;
#pragma unroll
    for (int oc = 0; oc < 8; oc++) {
        int o = oc * 16 + (lane & 15);
        float bv = bias[o];
#pragma unroll
        for (int j = 0; j < 4; j++) {
            float v = fmaxf(acc[oc][j] + bv, 0.0f);
            st[rl + j][o] = f2bf(v);
        }
    }
    __syncthreads();
    const int bRow0 = blockIdx.x * 64;
    const int t = threadIdx.x;
#pragma unroll
    for (int i = 0; i < 2; i++) {
        int c = t + i * 256;
        int r = c >> 3;
        int pos = (c & 7) * 16;
        int node = bRow0 + r;
        if (node < N) {
            short8 v0 = *(const short8*)&st[r][pos];
            short8 v1 = *(const short8*)&st[r][pos + 8];
            unsigned int w[4];
#pragma unroll
            for (int q = 0; q < 2; q++) {
                w[q] = (unsigned int)f2fp8(bf2f((unsigned short)v0[q * 4 + 0])) |
                       ((unsigned int)f2fp8(bf2f((unsigned short)v0[q * 4 + 1])) << 8) |
                       ((unsigned int)f2fp8(bf2f((unsigned short)v0[q * 4 + 2])) << 16) |
                       ((unsigned int)f2fp8(bf2f((unsigned short)v0[q * 4 + 3])) << 24);
                w[q + 2] = (unsigned int)f2fp8(bf2f((unsigned short)v1[q * 4 + 0])) |
                           ((unsigned int)f2fp8(bf2f((unsigned short)v1[q * 4 + 1])) << 8) |
                           ((unsigned int)f2fp8(bf2f((unsigned short)v1[q * 4 + 2])) << 16) |
                           ((unsigned int)f2fp8(bf2f((unsigned short)v1[q * 4 + 3])) << 24);
            }
            uint4 u;
            u.x = w[0]; u.y = w[1]; u.z = w[2]; u.w = w[3];
            *(uint4*)(outq + (size_t)node * 128 + pos) = u;
        }
    }
}

// layer-2 split transform (fp8 input): t2 = h @ Wl2^T (fp8), self = h @ Wr2^T + bl2 (f32)
__global__ __launch_bounds__(256) void k_xform2(const unsigned char* featq,
                                                const unsigned short* wf,
                                                const float* bias,
                                                unsigned char* t2q, float* out, int N) {
    __shared__ unsigned short st[64][68];
    const int wave = threadIdx.x >> 6;
    const int lane = threadIdx.x & 63;
    const int nodeBase = blockIdx.x * 64 + wave * 16;
    const int row = nodeBase + (lane & 15);
    const int kq = lane >> 4;
    floatx4 acc[8];
#pragma unroll
    for (int i = 0; i < 8; i++) acc[i] = (floatx4)0.0f;
    const bool rowOK = row < N;
    const unsigned char* frow = featq + (size_t)row * 128;
    const short8* bbase = (const short8*)wf;
#pragma unroll
    for (int ks = 0; ks < 4; ks++) {
        short8 a;
        if (rowOK)
            a = fp8x8_to_bf16x8(*(const uint2*)(frow + ks * 32 + kq * 8));
        else
            a = (short8)0;
#pragma unroll
        for (int oc = 0; oc < 8; oc++) {
            short8 b = bbase[(ks * 8 + oc) * 64 + lane];
            acc[oc] = __builtin_amdgcn_mfma_f32_16x16x32_bf16(a, b, acc[oc], 0, 0, 0);
        }
    }
    const int rl = wave * 16 + kq * 4;
    const int o16 = lane & 15;
#pragma unroll
    for (int oc = 0; oc < 8; oc++) {
#pragma unroll
        for (int j = 0; j < 4; j++) {
            int node = nodeBase + kq * 4 + j;
            if (oc < 4) {
                st[rl + j][oc * 16 + o16] = f2bf(acc[oc][j]);
            } else if (node < N) {
                int o = (oc - 4) * 16 + o16;
                out[(size_t)node * 64 + o] = acc[oc][j] + bias[o];
            }
        }
    }
    __syncthreads();
    const int bRow0 = blockIdx.x * 64;
    const int t = threadIdx.x;
    {
        int r = t >> 2;
        int pos = (t & 3) * 16;
        int node = bRow0 + r;
        if (node < N) {
            short8 v0 = *(const short8*)&st[r][pos];
            short8 v1 = *(const short8*)&st[r][pos + 8];
            unsigned int w[4];
#pragma unroll
            for (int q = 0; q < 2; q++) {
                w[q] = (unsigned int)f2fp8(bf2f((unsigned short)v0[q * 4 + 0])) |
                       ((unsigned int)f2fp8(bf2f((unsigned short)v0[q * 4 + 1])) << 8) |
                       ((unsigned int)f2fp8(bf2f((unsigned short)v0[q * 4 + 2])) << 16) |
                       ((unsigned int)f2fp8(bf2f((unsigned short)v0[q * 4 + 3])) << 24);
                w[q + 2] = (unsigned int)f2fp8(bf2f((unsigned short)v1[q * 4 + 0])) |
                           ((unsigned int)f2fp8(bf2f((unsigned short)v1[q * 4 + 1])) << 8) |
                           ((unsigned int)f2fp8(bf2f((unsigned short)v1[q * 4 + 2])) << 16) |
                           ((unsigned int)f2fp8(bf2f((unsigned short)v1[q * 4 + 3])) << 24);
            }
            uint4 u;
            u.x = w[0]; u.y = w[1]; u.z = w[2]; u.w = w[3];
            *(uint4*)(t2q + (size_t)node * 64 + pos) = u;
        }
    }
}

// 64-wide fp8 mean aggregation of t2 + add self + fused log_softmax (16-lane group/node)
__global__ __launch_bounds__(256) void k_aggr64lsm(const unsigned char* t2q, const int* rowptr,
                                                   const int* adj, float* out, int N) {
    int g = (blockIdx.x * blockDim.x + threadIdx.x) >> 4;
    int lane = threadIdx.x & 15;
    if (g >= N) return;
    int lo = rowptr[g], hi = rowptr[g + 1];
    float a0 = 0.f, a1 = 0.f, a2 = 0.f, a3 = 0.f;
    const unsigned char* fb = t2q + lane * 4;
    int j = lo;
    for (; j + 8 <= hi; j += 8) {
        unsigned int v[8];
#pragma unroll
        for (int u = 0; u < 8; u++) {
            int s = adj[j + u];
            v[u] = *(const unsigned int*)(fb + (size_t)s * 64);
        }
#pragma unroll
        for (int u = 0; u < 8; u++) {
            floatx2 l2 = fp8pk2f<false>(v[u]);
            floatx2 h2 = fp8pk2f<true>(v[u]);
            a0 += l2[0]; a1 += l2[1]; a2 += h2[0]; a3 += h2[1];
        }
    }
    if (j < hi) {
        unsigned int v[8];
        float w[8];
#pragma unroll
        for (int u = 0; u < 8; u++) {
            int jj = j + u;
            int s = adj[jj < hi ? jj : hi - 1];
            v[u] = *(const unsigned int*)(fb + (size_t)s * 64);
            w[u] = (jj < hi) ? 1.0f : 0.0f;
        }
#pragma unroll
        for (int u = 0; u < 8; u++) {
            floatx2 l2 = fp8pk2f<false>(v[u]);
            floatx2 h2 = fp8pk2f<true>(v[u]);
            a0 = fmaf(w[u], l2[0], a0);
            a1 = fmaf(w[u], l2[1], a1);
            a2 = fmaf(w[u], h2[0], a2);
            a3 = fmaf(w[u], h2[1], a3);
        }
    }
    float inv = 1.0f / (float)max(hi - lo, 1);
    float* op = out + (size_t)g * 64 + lane * 4;
    float4 cur = *(float4*)op;
    float v0 = cur.x + a0 * inv, v1 = cur.y + a1 * inv;
    float v2 = cur.z + a2 * inv, v3 = cur.w + a3 * inv;
    float m = fmaxf(fmaxf(v0, v1), fmaxf(v2, v3));
#pragma unroll
    for (int off = 8; off; off >>= 1) m = fmaxf(m, __shfl_xor(m, off));
    float s = expf(v0 - m) + expf(v1 - m) + expf(v2 - m) + expf(v3 - m);
#pragma unroll
    for (int off = 8; off; off >>= 1) s += __shfl_xor(s, off);
    float ls = m + logf(s);
    float4 o;
    o.x = v0 - ls; o.y = v1 - ls; o.z = v2 - ls; o.w = v3 - ls;
    *(float4*)op = o;
}

extern "C" void kernel_launch(void* const* d_in, const int* in_sizes, int n_in,
                              void* d_out, int out_size, void* d_ws, size_t ws_size,
                              hipStream_t stream) {
    const float* x = (const float*)d_in[0];
    const int* ei = (const int*)d_in[1];
    const float* Wl0 = (const float*)d_in[2];
    const float* bl0 = (const float*)d_in[3];
    const float* Wr0 = (const float*)d_in[4];
    const float* Wl1 = (const float*)d_in[5];
    const float* bl1 = (const float*)d_in[6];
    const float* Wr1 = (const float*)d_in[7];
    const float* Wl2 = (const float*)d_in[8];
    const float* bl2 = (const float*)d_in[9];
    const float* Wr2 = (const float*)d_in[10];

    int N = in_sizes[0] / 128;
    int E = in_sizes[1] / 2;
    const int* src = ei;
    const int* dst = ei + E;

    char* ws = (char*)d_ws;
    size_t off = 0;
    auto alloc = [&](size_t bytes) {
        void* p = ws + off;
        off += (bytes + 255) & ~(size_t)255;
        return p;
    };
    int* cnt = (int*)alloc((size_t)CB * CB * 4);
    int* cntoff = (int*)alloc(((size_t)CB * CB + 1) * 4);
    int* bsum = (int*)alloc(CB * 4);
    unsigned int* ebuf = (unsigned int*)alloc((size_t)E * 4);
    int* rowptr = (int*)alloc((size_t)(N + 1) * 4);
    int* adj = (int*)alloc((size_t)E * 4);
    unsigned char* abuf = (unsigned char*)alloc((size_t)N * 128);  // fp8 aggr; reused as fp8 t2
    unsigned char* q8a = (unsigned char*)alloc((size_t)N * 128);   // fp8(x)
    unsigned char* q8b = (unsigned char*)alloc((size_t)N * 128);   // fp8(h0)
    unsigned char* q8c = (unsigned char*)alloc((size_t)N * 128);   // fp8(h1)
    unsigned short* w0 = (unsigned short*)alloc(8 * 8 * 64 * 8 * 2);
    unsigned short* w1 = (unsigned short*)alloc(8 * 8 * 64 * 8 * 2);
    unsigned short* w2 = (unsigned short*)alloc(4 * 8 * 64 * 8 * 2);

    // ---- fused CSR build + prep (one cooperative launch) ----
    int n4 = N * 32;  // number of 4-float groups in x
    {
        void* args[] = {
            (void*)&src, (void*)&dst, (void*)&E,
            (void*)&cnt, (void*)&cntoff, (void*)&bsum, (void*)&ebuf,
            (void*)&rowptr, (void*)&adj, (void*)&N,
            (void*)&x, (void*)&q8a, (void*)&n4,
            (void*)&Wl0, (void*)&Wr0, (void*)&w0,
            (void*)&Wl1, (void*)&Wr1, (void*)&w1,
            (void*)&Wl2, (void*)&Wr2, (void*)&w2,
        };
        hipLaunchCooperativeKernel((const void*)k_csr, dim3(CB), dim3(256), args, 0, stream);
    }

    const int aggrGrid = ((N * 32) + 255) / 256;
    const int aggr64Grid = ((N * 16) + 255) / 256;
    const int xfGrid = (N + 63) / 64;

    unsigned char* aggr = abuf;
    unsigned char* t2q = abuf;

    // layer 0: gather fp8(x) -> fp8 mean; xform([aggr|x]) -> fp8(h0)
    k_aggr8<<<aggrGrid, 256, 0, stream>>>(q8a, rowptr, adj, aggr, N);
    k_xform<<<xfGrid, 256, 0, stream>>>(aggr, q8a, w0, bl0, q8b, N);
    // layer 1: gather fp8(h0) -> fp8 mean; xform([aggr|h0]) -> fp8(h1)
    k_aggr8<<<aggrGrid, 256, 0, stream>>>(q8b, rowptr, adj, aggr, N);
    k_xform<<<xfGrid, 256, 0, stream>>>(aggr, q8b, w1, bl1, q8c, N);
    // layer 2: transform first (commutes with mean), then fused fp8 aggregate + log_softmax
    k_xform2<<<xfGrid, 256, 0, stream>>>(q8c, w2, bl2, t2q, (float*)d_out, N);
    k_aggr64lsm<<<aggr64Grid, 256, 0, stream>>>(t2q, rowptr, adj, (float*)d_out, N);
}

// Round 14
// 238.776 us; speedup vs baseline: 2.2644x; 2.2644x over previous
//
#include <hip/hip_runtime.h>
#include <hip/hip_bf16.h>
#include <math.h>

typedef __attribute__((ext_vector_type(8))) short short8;
typedef __attribute__((ext_vector_type(4))) float floatx4;
typedef __attribute__((ext_vector_type(2))) float floatx2;
typedef __attribute__((ext_vector_type(4))) unsigned short ushortx4;

__device__ __forceinline__ float bf2f(unsigned short u) {
    union { unsigned int i; float f; } c; c.i = ((unsigned int)u) << 16; return c.f;
}
__device__ __forceinline__ unsigned short f2bf(float f) {
    union { float f; unsigned int i; } c; c.f = f;
    unsigned int x = c.i;
    return (unsigned short)((x + 0x7FFFu + ((x >> 16) & 1u)) >> 16);
}

// ---------- fp8 e4m3fn (OCP) encode/decode ----------
__device__ __forceinline__ unsigned char f2fp8(float f) {
    unsigned int u = __float_as_uint(f);
    unsigned int sign = (u >> 24) & 0x80u;
    unsigned int a = u & 0x7FFFFFFFu;
    if (a >= 0x43E00000u) return (unsigned char)(sign | 0x7Eu);  // saturate at 448
    if (a < 0x3C800000u) {  // below smallest normal 2^-6: denormal units of 2^-9
        int unit = (int)rintf(__uint_as_float(a) * 512.0f);
        return (unsigned char)(sign | (unsigned int)unit);
    }
    unsigned int r = a + 0x7FFFFu + ((a >> 20) & 1u);  // RNE at bit 20
    unsigned int e = (r >> 23) - 120u;
    unsigned int m = (r >> 20) & 7u;
    return (unsigned char)(sign | (e << 3) | m);
}

__device__ __forceinline__ float fp8dec1(unsigned int b) {
    unsigned int s = (b & 0x80u) << 24;
    unsigned int mag = (b & 0x7Fu) << 20;
    return __uint_as_float(s | mag) * __uint_as_float(0x7B800000u);  // * 2^120
}

template <bool W>
__device__ __forceinline__ floatx2 fp8pk2f(unsigned int v) {
#if defined(__has_builtin) && __has_builtin(__builtin_amdgcn_cvt_pk_f32_fp8)
    return __builtin_amdgcn_cvt_pk_f32_fp8(v, W);
#else
    floatx2 r;
    r[0] = fp8dec1((v >> (W ? 16 : 0)) & 0xFFu);
    r[1] = fp8dec1((v >> (W ? 24 : 8)) & 0xFFu);
    return r;
#endif
}

// decode 8 fp8 (as uint2) -> bf16x8 MFMA A-fragment (exact: e4m3 subset of bf16)
__device__ __forceinline__ short8 fp8x8_to_bf16x8(uint2 q) {
    floatx2 p0 = fp8pk2f<false>(q.x), p1 = fp8pk2f<true>(q.x);
    floatx2 p2 = fp8pk2f<false>(q.y), p3 = fp8pk2f<true>(q.y);
    short8 a;
    a[0] = (short)f2bf(p0[0]); a[1] = (short)f2bf(p0[1]);
    a[2] = (short)f2bf(p1[0]); a[3] = (short)f2bf(p1[1]);
    a[4] = (short)f2bf(p2[0]); a[5] = (short)f2bf(p2[1]);
    a[6] = (short)f2bf(p3[0]); a[7] = (short)f2bf(p3[1]);
    return a;
}

// pack 16 bf16 (two short8) -> 16 fp8 bytes as uint4
__device__ __forceinline__ uint4 pack16_fp8(short8 v0, short8 v1) {
    unsigned int w[4];
#pragma unroll
    for (int q = 0; q < 2; q++) {
        w[q] = (unsigned int)f2fp8(bf2f((unsigned short)v0[q * 4 + 0])) |
               ((unsigned int)f2fp8(bf2f((unsigned short)v0[q * 4 + 1])) << 8) |
               ((unsigned int)f2fp8(bf2f((unsigned short)v0[q * 4 + 2])) << 16) |
               ((unsigned int)f2fp8(bf2f((unsigned short)v0[q * 4 + 3])) << 24);
        w[q + 2] = (unsigned int)f2fp8(bf2f((unsigned short)v1[q * 4 + 0])) |
                   ((unsigned int)f2fp8(bf2f((unsigned short)v1[q * 4 + 1])) << 8) |
                   ((unsigned int)f2fp8(bf2f((unsigned short)v1[q * 4 + 2])) << 16) |
                   ((unsigned int)f2fp8(bf2f((unsigned short)v1[q * 4 + 3])) << 24);
    }
    uint4 u;
    u.x = w[0]; u.y = w[1]; u.z = w[2]; u.w = w[3];
    return u;
}

// ================= bucketed CSR build =================
constexpr int NB = 512;
constexpr int B1 = 256;

__global__ __launch_bounds__(256) void k_bhist(const int* dst, int E, int* cnt) {
    __shared__ int h[NB];
    int t = threadIdx.x, b = blockIdx.x;
    h[t] = 0; h[t + 256] = 0;
    __syncthreads();
    int chunk = (E + B1 - 1) / B1;
    int lo = b * chunk, hi = min(E, lo + chunk);
    for (int e = lo + t; e < hi; e += 256) atomicAdd(&h[dst[e] >> 8], 1);
    __syncthreads();
    cnt[(size_t)t * B1 + b] = h[t];
    cnt[(size_t)(t + 256) * B1 + b] = h[t + 256];
}

constexpr int SCAN_T = 256;
constexpr int SCAN_V = 8;
constexpr int SCAN_CHUNK = SCAN_T * SCAN_V;

__global__ void k_scan_part(const int* in, int* bsum, int N) {
    int b = blockIdx.x, t = threadIdx.x;
    int base = b * SCAN_CHUNK + t * SCAN_V;
    int s = 0;
#pragma unroll
    for (int j = 0; j < SCAN_V; j++) {
        int i = base + j;
        if (i < N) s += in[i];
    }
    __shared__ int wsums[SCAN_T / 64];
    for (int off = 32; off; off >>= 1) s += __shfl_down(s, off, 64);
    if ((t & 63) == 0) wsums[t >> 6] = s;
    __syncthreads();
    if (t == 0) {
        int tot = 0;
#pragma unroll
        for (int w = 0; w < SCAN_T / 64; w++) tot += wsums[w];
        bsum[b] = tot;
    }
}

__global__ void k_scan_top(int* bsum, int nb) {
    if (threadIdx.x == 0) {
        int run = 0;
        for (int i = 0; i < nb; i++) {
            int v = bsum[i];
            bsum[i] = run;
            run += v;
        }
    }
}

__global__ void k_scan_apply(const int* in, const int* bsum, int* out, int N) {
    int b = blockIdx.x, t = threadIdx.x;
    int base = b * SCAN_CHUNK + t * SCAN_V;
    int v[SCAN_V];
    int s = 0;
#pragma unroll
    for (int j = 0; j < SCAN_V; j++) {
        int i = base + j;
        v[j] = (i < N) ? in[i] : 0;
        s += v[j];
    }
    __shared__ int sums[SCAN_T];
    sums[t] = s;
    __syncthreads();
    for (int off = 1; off < SCAN_T; off <<= 1) {
        int x = (t >= off) ? sums[t - off] : 0;
        __syncthreads();
        sums[t] += x;
        __syncthreads();
    }
    int pre = bsum[b] + ((t == 0) ? 0 : sums[t - 1]);
#pragma unroll
    for (int j = 0; j < SCAN_V; j++) {
        int i = base + j;
        if (i < N) {
            out[i] = pre;
            pre += v[j];
            if (i == N - 1) out[N] = pre;
        }
    }
}

__global__ __launch_bounds__(256) void k_bscatter(const int* src, const int* dst, int E,
                                                  const int* cntoff, unsigned int* ebuf) {
    __shared__ int base[NB];
    __shared__ int lcur[NB];
    int t = threadIdx.x, b = blockIdx.x;
    for (int i = t; i < NB; i += 256) {
        base[i] = cntoff[(size_t)i * B1 + b];
        lcur[i] = 0;
    }
    __syncthreads();
    int chunk = (E + B1 - 1) / B1;
    int lo = b * chunk, hi = min(E, lo + chunk);
    for (int e = lo + t; e < hi; e += 256) {
        int d = dst[e];
        int cb = d >> 8;
        int slot = atomicAdd(&lcur[cb], 1);
        ebuf[base[cb] + slot] = (unsigned int)src[e] | ((unsigned int)(d & 255) << 17);
    }
}

__global__ __launch_bounds__(256) void k_build(const unsigned int* ebuf, const int* cntoff,
                                               int* rowptr, int* adj, int N, int E) {
    __shared__ int ldeg[256];
    __shared__ int lptr[256];
    __shared__ int lcur[256];
    __shared__ int tsum[256];
    int t = threadIdx.x, cb = blockIdx.x;
    int bbase = cntoff[(size_t)cb * B1];
    int bend = cntoff[(size_t)(cb + 1) * B1];
    ldeg[t] = 0;
    lcur[t] = 0;
    __syncthreads();
    for (int e = bbase + t; e < bend; e += 256) atomicAdd(&ldeg[ebuf[e] >> 17], 1);
    __syncthreads();
    tsum[t] = ldeg[t];
    __syncthreads();
    for (int off = 1; off < 256; off <<= 1) {
        int v = (t >= off) ? tsum[t - off] : 0;
        __syncthreads();
        tsum[t] += v;
        __syncthreads();
    }
    lptr[t] = tsum[t] - ldeg[t];
    __syncthreads();
    int node = cb * 256 + t;
    if (node < N) rowptr[node] = bbase + lptr[t];
    if (cb == 0 && t == 0) rowptr[N] = E;
    for (int e = bbase + t; e < bend; e += 256) {
        unsigned int pk = ebuf[e];
        int dl = pk >> 17;
        int ls = atomicAdd(&lcur[dl], 1);
        adj[bbase + lptr[dl] + ls] = (int)(pk & 0x1FFFF);
    }
}

// ---------------- combined prep: x->fp8 conversion AND 3x weight prep ----------------
__device__ __forceinline__ void prep_w_body(const float* Wl, const float* Wr,
                                            unsigned short* wf, int NOC, int t) {
    int total = 8 * NOC * 64 * 8;
    if (t >= total) return;
    int j = t & 7;
    int lane = (t >> 3) & 63;
    int rest = t >> 9;
    int oc = rest % NOC;
    int ks = rest / NOC;
    int k = ks * 32 + ((lane >> 4) << 3) + j;
    int o = oc * 16 + (lane & 15);
    float v = (k < 128) ? Wl[o * 128 + k] : Wr[o * 128 + (k - 128)];
    wf[t] = f2bf(v);
}

__device__ __forceinline__ void prep_w2_body(const float* Wl, const float* Wr,
                                             unsigned short* wf, int t) {
    int total = 4 * 8 * 64 * 8;
    if (t >= total) return;
    int j = t & 7;
    int lane = (t >> 3) & 63;
    int rest = t >> 9;
    int oc = rest % 8;
    int ks = rest / 8;
    int k = ks * 32 + ((lane >> 4) << 3) + j;
    int o16 = lane & 15;
    float v = (oc < 4) ? Wl[(oc * 16 + o16) * 128 + k] : Wr[((oc - 4) * 16 + o16) * 128 + k];
    wf[t] = f2bf(v);
}

__global__ __launch_bounds__(256) void k_prep(const float* x, unsigned char* xq, int n4,
                                              const float* Wl0, const float* Wr0, unsigned short* w0,
                                              const float* Wl1, const float* Wr1, unsigned short* w1,
                                              const float* Wl2, const float* Wr2, unsigned short* w2,
                                              int cvtBlocks) {
    int b = blockIdx.x;
    if (b < cvtBlocks) {
        int i = b * 256 + threadIdx.x;
        int idx = i * 4;
        if (idx < n4 * 4) {
            float4 v = *(const float4*)(x + idx);
            unsigned int qw = (unsigned int)f2fp8(v.x) | ((unsigned int)f2fp8(v.y) << 8) |
                              ((unsigned int)f2fp8(v.z) << 16) | ((unsigned int)f2fp8(v.w) << 24);
            *(unsigned int*)(xq + idx) = qw;
        }
    } else if (b < cvtBlocks + 128) {
        prep_w_body(Wl0, Wr0, w0, 8, (b - cvtBlocks) * 256 + threadIdx.x);
    } else if (b < cvtBlocks + 256) {
        prep_w_body(Wl1, Wr1, w1, 8, (b - cvtBlocks - 128) * 256 + threadIdx.x);
    } else {
        prep_w2_body(Wl2, Wr2, w2, (b - cvtBlocks - 256) * 256 + threadIdx.x);
    }
}

// ---------------- fp8 mean aggregation -> fp8 mean (32-lane group per node) ----------------
__global__ __launch_bounds__(256) void k_aggr8(const unsigned char* feat, const int* rowptr,
                                               const int* adj, unsigned char* aggr, int N) {
    int g = (blockIdx.x * blockDim.x + threadIdx.x) >> 5;
    int lane = threadIdx.x & 31;
    if (g >= N) return;
    int lo = rowptr[g], hi = rowptr[g + 1];
    float a0 = 0.f, a1 = 0.f, a2 = 0.f, a3 = 0.f;
    const unsigned char* fb = feat + lane * 4;
    int j = lo;
    for (; j + 8 <= hi; j += 8) {
        unsigned int v[8];
#pragma unroll
        for (int u = 0; u < 8; u++) {
            int s = adj[j + u];
            v[u] = *(const unsigned int*)(fb + (size_t)s * 128);
        }
#pragma unroll
        for (int u = 0; u < 8; u++) {
            floatx2 l2 = fp8pk2f<false>(v[u]);
            floatx2 h2 = fp8pk2f<true>(v[u]);
            a0 += l2[0]; a1 += l2[1]; a2 += h2[0]; a3 += h2[1];
        }
    }
    if (j < hi) {  // masked tail chunk: loads issued back-to-back
        unsigned int v[8];
        float w[8];
#pragma unroll
        for (int u = 0; u < 8; u++) {
            int jj = j + u;
            int s = adj[jj < hi ? jj : hi - 1];
            v[u] = *(const unsigned int*)(fb + (size_t)s * 128);
            w[u] = (jj < hi) ? 1.0f : 0.0f;
        }
#pragma unroll
        for (int u = 0; u < 8; u++) {
            floatx2 l2 = fp8pk2f<false>(v[u]);
            floatx2 h2 = fp8pk2f<true>(v[u]);
            a0 = fmaf(w[u], l2[0], a0);
            a1 = fmaf(w[u], l2[1], a1);
            a2 = fmaf(w[u], h2[0], a2);
            a3 = fmaf(w[u], h2[1], a3);
        }
    }
    float inv = 1.0f / (float)max(hi - lo, 1);
    unsigned int qw = (unsigned int)f2fp8(a0 * inv) | ((unsigned int)f2fp8(a1 * inv) << 8) |
                      ((unsigned int)f2fp8(a2 * inv) << 16) | ((unsigned int)f2fp8(a3 * inv) << 24);
    *(unsigned int*)(aggr + (size_t)g * 128 + lane * 4) = qw;
}

// ---------------- fused transform: h = relu([aggr|feat] @ W + b) ----------------
// STAGE2=false: write fp8(h) to outq (layer 0).
// STAGE2=true (layer 1): additionally compute layer 2 from the LDS h-tile:
//   t2 = h @ Wl2^T (fp8 -> t2q),  self = h @ Wr2^T + bl2 (f32 -> outf).  h never hits HBM.
template <bool STAGE2>
__global__ __launch_bounds__(256) void k_xform(const unsigned char* aggr,
                                               const unsigned char* featq,
                                               const unsigned short* w2f,
                                               const float* bias, unsigned char* outq,
                                               const unsigned short* wf2, const float* bias2,
                                               unsigned char* t2q, float* outf, int N) {
    __shared__ unsigned short st[64][132];
    const int wave = threadIdx.x >> 6;
    const int lane = threadIdx.x & 63;
    const int rloc = wave * 16 + (lane & 15);
    const int row = blockIdx.x * 64 + rloc;
    const int kq = lane >> 4;
    floatx4 acc[8];
#pragma unroll
    for (int i = 0; i < 8; i++) acc[i] = (floatx4)0.0f;
    const bool rowOK = row < N;
    const unsigned char* arow = aggr + (size_t)row * 128;
    const unsigned char* frow = featq + (size_t)row * 128;
    const short8* bbase = (const short8*)w2f;
#pragma unroll
    for (int ks = 0; ks < 8; ks++) {
        short8 a;
        if (!rowOK) {
            a = (short8)0;
        } else {
            const unsigned char* p =
                (ks < 4) ? (arow + ks * 32 + kq * 8) : (frow + (ks - 4) * 32 + kq * 8);
            a = fp8x8_to_bf16x8(*(const uint2*)p);
        }
#pragma unroll
        for (int oc = 0; oc < 8; oc++) {
            short8 b = bbase[(ks * 8 + oc) * 64 + lane];
            acc[oc] = __builtin_amdgcn_mfma_f32_16x16x32_bf16(a, b, acc[oc], 0, 0, 0);
        }
    }
    const int rl = wave * 16 + kq * 4;
#pragma unroll
    for (int oc = 0; oc < 8; oc++) {
        int o = oc * 16 + (lane & 15);
        float bv = bias[o];
#pragma unroll
        for (int j = 0; j < 4; j++) {
            float v = fmaxf(acc[oc][j] + bv, 0.0f);
            st[rl + j][o] = f2bf(v);
        }
    }
    __syncthreads();
    const int bRow0 = blockIdx.x * 64;
    const int t = threadIdx.x;
    if (!STAGE2) {
        // coalesced fp8 h stores: 512 chunks of 16 B
#pragma unroll
        for (int i = 0; i < 2; i++) {
            int c = t + i * 256;
            int r = c >> 3;
            int pos = (c & 7) * 16;
            int node = bRow0 + r;
            if (node < N) {
                short8 v0 = *(const short8*)&st[r][pos];
                short8 v1 = *(const short8*)&st[r][pos + 8];
                *(uint4*)(outq + (size_t)node * 128 + pos) = pack16_fp8(v0, v1);
            }
        }
    } else {
        // ---- stage 2: layer-2 transform from LDS h-tile (bf16, exact) ----
        floatx4 acc2[8];
#pragma unroll
        for (int i = 0; i < 8; i++) acc2[i] = (floatx4)0.0f;
        const short8* bbase2 = (const short8*)wf2;
#pragma unroll
        for (int ks = 0; ks < 4; ks++) {
            short8 a = *(const short8*)&st[rloc][ks * 32 + kq * 8];
#pragma unroll
            for (int oc = 0; oc < 8; oc++) {
                short8 b = bbase2[(ks * 8 + oc) * 64 + lane];
                acc2[oc] = __builtin_amdgcn_mfma_f32_16x16x32_bf16(a, b, acc2[oc], 0, 0, 0);
            }
        }
        __syncthreads();  // done reading h from st; safe to overwrite
        const int o16 = lane & 15;
#pragma unroll
        for (int oc = 0; oc < 8; oc++) {
#pragma unroll
            for (int j = 0; j < 4; j++) {
                int node = bRow0 + wave * 16 + kq * 4 + j;
                if (oc < 4) {
                    st[rl + j][oc * 16 + o16] = f2bf(acc2[oc][j]);  // t2 tile (cols 0..63)
                } else if (node < N) {
                    int o = (oc - 4) * 16 + o16;
                    outf[(size_t)node * 64 + o] = acc2[oc][j] + bias2[o];  // self + bias (full-line)
                }
            }
        }
        __syncthreads();
        // coalesced fp8 t2 stores: 256 chunks of 16 B (64 rows x 64 B)
        {
            int r = t >> 2;
            int pos = (t & 3) * 16;
            int node = bRow0 + r;
            if (node < N) {
                short8 v0 = *(const short8*)&st[r][pos];
                short8 v1 = *(const short8*)&st[r][pos + 8];
                *(uint4*)(t2q + (size_t)node * 64 + pos) = pack16_fp8(v0, v1);
            }
        }
    }
}

// 64-wide fp8 mean aggregation of t2 + add self + fused log_softmax (16-lane group/node)
__global__ __launch_bounds__(256) void k_aggr64lsm(const unsigned char* t2q, const int* rowptr,
                                                   const int* adj, float* out, int N) {
    int g = (blockIdx.x * blockDim.x + threadIdx.x) >> 4;
    int lane = threadIdx.x & 15;
    if (g >= N) return;
    int lo = rowptr[g], hi = rowptr[g + 1];
    float a0 = 0.f, a1 = 0.f, a2 = 0.f, a3 = 0.f;
    const unsigned char* fb = t2q + lane * 4;
    int j = lo;
    for (; j + 8 <= hi; j += 8) {
        unsigned int v[8];
#pragma unroll
        for (int u = 0; u < 8; u++) {
            int s = adj[j + u];
            v[u] = *(const unsigned int*)(fb + (size_t)s * 64);
        }
#pragma unroll
        for (int u = 0; u < 8; u++) {
            floatx2 l2 = fp8pk2f<false>(v[u]);
            floatx2 h2 = fp8pk2f<true>(v[u]);
            a0 += l2[0]; a1 += l2[1]; a2 += h2[0]; a3 += h2[1];
        }
    }
    if (j < hi) {
        unsigned int v[8];
        float w[8];
#pragma unroll
        for (int u = 0; u < 8; u++) {
            int jj = j + u;
            int s = adj[jj < hi ? jj : hi - 1];
            v[u] = *(const unsigned int*)(fb + (size_t)s * 64);
            w[u] = (jj < hi) ? 1.0f : 0.0f;
        }
#pragma unroll
        for (int u = 0; u < 8; u++) {
            floatx2 l2 = fp8pk2f<false>(v[u]);
            floatx2 h2 = fp8pk2f<true>(v[u]);
            a0 = fmaf(w[u], l2[0], a0);
            a1 = fmaf(w[u], l2[1], a1);
            a2 = fmaf(w[u], h2[0], a2);
            a3 = fmaf(w[u], h2[1], a3);
        }
    }
    float inv = 1.0f / (float)max(hi - lo, 1);
    float* op = out + (size_t)g * 64 + lane * 4;
    float4 cur = *(float4*)op;
    float v0 = cur.x + a0 * inv, v1 = cur.y + a1 * inv;
    float v2 = cur.z + a2 * inv, v3 = cur.w + a3 * inv;
    float m = fmaxf(fmaxf(v0, v1), fmaxf(v2, v3));
#pragma unroll
    for (int off = 8; off; off >>= 1) m = fmaxf(m, __shfl_xor(m, off));
    float s = expf(v0 - m) + expf(v1 - m) + expf(v2 - m) + expf(v3 - m);
#pragma unroll
    for (int off = 8; off; off >>= 1) s += __shfl_xor(s, off);
    float ls = m + logf(s);
    float4 o;
    o.x = v0 - ls; o.y = v1 - ls; o.z = v2 - ls; o.w = v3 - ls;
    *(float4*)op = o;
}

extern "C" void kernel_launch(void* const* d_in, const int* in_sizes, int n_in,
                              void* d_out, int out_size, void* d_ws, size_t ws_size,
                              hipStream_t stream) {
    const float* x = (const float*)d_in[0];
    const int* ei = (const int*)d_in[1];
    const float* Wl0 = (const float*)d_in[2];
    const float* bl0 = (const float*)d_in[3];
    const float* Wr0 = (const float*)d_in[4];
    const float* Wl1 = (const float*)d_in[5];
    const float* bl1 = (const float*)d_in[6];
    const float* Wr1 = (const float*)d_in[7];
    const float* Wl2 = (const float*)d_in[8];
    const float* bl2 = (const float*)d_in[9];
    const float* Wr2 = (const float*)d_in[10];

    const int N = in_sizes[0] / 128;
    const int E = in_sizes[1] / 2;
    const int* src = ei;
    const int* dst = ei + E;

    char* ws = (char*)d_ws;
    size_t off = 0;
    auto alloc = [&](size_t bytes) {
        void* p = ws + off;
        off += (bytes + 255) & ~(size_t)255;
        return p;
    };
    int* cntin = (int*)alloc((size_t)NB * B1 * 4);
    int* cntoff = (int*)alloc(((size_t)NB * B1 + 1) * 4);
    int* bsum = (int*)alloc(1024 * 4);
    unsigned int* ebuf = (unsigned int*)alloc((size_t)E * 4);
    int* rowptr = (int*)alloc((size_t)(N + 1) * 4);
    int* adj = (int*)alloc((size_t)E * 4);
    unsigned char* abuf = (unsigned char*)alloc((size_t)N * 128);  // fp8 aggr; reused as fp8 t2
    unsigned char* q8a = (unsigned char*)alloc((size_t)N * 128);   // fp8(x)
    unsigned char* q8b = (unsigned char*)alloc((size_t)N * 128);   // fp8(h0)
    unsigned short* w0 = (unsigned short*)alloc(8 * 8 * 64 * 8 * 2);
    unsigned short* w1 = (unsigned short*)alloc(8 * 8 * 64 * 8 * 2);
    unsigned short* w2 = (unsigned short*)alloc(4 * 8 * 64 * 8 * 2);

    // ---- bucketed CSR build (split kernels: proven fast; cooperative fusion regressed) ----
    const int NBUCK = (N + 255) >> 8;
    k_bhist<<<B1, 256, 0, stream>>>(dst, E, cntin);
    const int scanLen = NB * B1;
    const int nScanBlocks = (scanLen + SCAN_CHUNK - 1) / SCAN_CHUNK;
    k_scan_part<<<nScanBlocks, SCAN_T, 0, stream>>>(cntin, bsum, scanLen);
    k_scan_top<<<1, 64, 0, stream>>>(bsum, nScanBlocks);
    k_scan_apply<<<nScanBlocks, SCAN_T, 0, stream>>>(cntin, bsum, cntoff, scanLen);
    k_bscatter<<<B1, 256, 0, stream>>>(src, dst, E, cntoff, ebuf);
    k_build<<<NBUCK, 256, 0, stream>>>(ebuf, cntoff, rowptr, adj, N, E);

    // combined conversion + weight prep (one launch)
    const int cvtBlocks = ((N * 128 / 4) + 255) / 256;
    k_prep<<<cvtBlocks + 128 + 128 + 64, 256, 0, stream>>>(
        x, q8a, N * 128 / 4, Wl0, Wr0, w0, Wl1, Wr1, w1, Wl2, Wr2, w2, cvtBlocks);

    const int aggrGrid = ((N * 32) + 255) / 256;
    const int aggr64Grid = ((N * 16) + 255) / 256;
    const int xfGrid = (N + 63) / 64;

    unsigned char* aggr = abuf;
    unsigned char* t2q = abuf;

    // layer 0: gather fp8(x) -> fp8 mean; xform([aggr|x]) -> fp8(h0)
    k_aggr8<<<aggrGrid, 256, 0, stream>>>(q8a, rowptr, adj, aggr, N);
    k_xform<false><<<xfGrid, 256, 0, stream>>>(aggr, q8a, w0, bl0, q8b,
                                               nullptr, nullptr, nullptr, nullptr, N);
    // layer 1: gather fp8(h0) -> fp8 mean; xform([aggr|h0]) -> h1 (LDS only)
    //          + fused layer-2 transform: t2q (fp8) + self (f32 -> d_out)
    k_aggr8<<<aggrGrid, 256, 0, stream>>>(q8b, rowptr, adj, aggr, N);
    k_xform<true><<<xfGrid, 256, 0, stream>>>(aggr, q8b, w1, bl1, nullptr,
                                              w2, bl2, t2q, (float*)d_out, N);
    // layer 2 aggregation: fused fp8 aggregate + log_softmax
    k_aggr64lsm<<<aggr64Grid, 256, 0, stream>>>(t2q, rowptr, adj, (float*)d_out, N);
}